// Round 7
// baseline (149.421 us; speedup 1.0000x reference)
//
#include <hip/hip_runtime.h>

#define EPSF 1e-5f

typedef int    int4v   __attribute__((ext_vector_type(4)));
typedef float  float4v __attribute__((ext_vector_type(4)));

// ---------- ws layout ----------
// qh1n : u8  [25088 pos][288 B]  nibble-packed conv1 output (ch = 2*byte + nibble)
// w1p  : i64 [36*3*64]   conv1 A-fragments (m=co)
// w3p  : i64 [6*18*64]   conv3 B-fragments (n=co)
// w2d  : i64 [36*5*64]   dw diagonal A-fragments (m=ch_local, k=(tap,c'), nibble-perm folded)
#define QH1N_OFF 0
#define W1P_OFF  7225344
#define W3P_OFF  7280640
#define W2D_OFF  7335936
#define S1B1_OFF 7428096
#define S2B2_OFF 7432704
#define S3B3_OFF 7437312

// K2 LDS strides (bytes).
// h1 slab: 90 rows (3 img rows x 30 halo cols) x 288B, stride 304 (16B-aligned; 76 w
//   === 12 mod 32, gcd 4 -> gather ~2-way = free).  h2: 32 pos x 600 (150 w === 22).
#define H1S 304
#define H2S 600

__device__ __forceinline__ float lsq_q(float v, float a) {
    float t = v / a;                       // real division (weight alphas not pow2)
    t = fminf(fmaxf(t, -8.0f), 7.0f);
    return rintf(t);                       // RNE == jnp.round
}

__device__ __forceinline__ long q8pack_w(const float* w, int base, float a) {
    unsigned long long v = 0;
    #pragma unroll
    for (int j = 0; j < 8; ++j) {
        int q = (int)lsq_q(w[base + j], a);
        v |= (unsigned long long)(q & 255) << (8 * j);
    }
    return (long)v;
}

// ---------------- prep: quantize/pack weights + fused epilogue constants ----------------
// i8 MFMA 16x16x32 fragment layout (HW-verified r2-r6): lane l holds 8 k-bytes
// k = (l>>4)*8 + j at m/n = l&15;  D: col = l&15, row = (l>>4)*4 + reg.
__global__ __launch_bounds__(256)
void prep_w(const float* __restrict__ w1, const float* __restrict__ w2,
            const float* __restrict__ w3,
            const float* aw1, const float* ax1, const float* ax2,
            const float* aw2, const float* ax3, const float* aw3,
            const float* __restrict__ g1, const float* __restrict__ b1,
            const float* __restrict__ m1, const float* __restrict__ v1,
            const float* __restrict__ g2, const float* __restrict__ b2,
            const float* __restrict__ m2, const float* __restrict__ v2,
            const float* __restrict__ g3, const float* __restrict__ b3,
            const float* __restrict__ m3, const float* __restrict__ v3,
            long* __restrict__ w1p, long* __restrict__ w3p,
            long* __restrict__ w2d,
            float* __restrict__ s1b1, float* __restrict__ s2b2,
            float* __restrict__ s3b3) {
    int id = blockIdx.x * 256 + threadIdx.x;
    if (id < 6912) {                        // w1p: ct 0..35, kc 0..2
        int l = id & 63, t = id >> 6;
        int kc = t % 3, ct = t / 3;
        int co = ct * 16 + (l & 15);
        int ci0 = kc * 32 + (l >> 4) * 8;
        w1p[id] = q8pack_w(w1, co * 96 + ci0, aw1[0]);
    } else if (id < 13824) {                // w3p: ct 0..5, kc 0..17
        int i = id - 6912;
        int l = i & 63, t = i >> 6;
        int kc = t % 18, ct = t / 18;
        int co = ct * 16 + (l & 15);
        int ci0 = kc * 32 + (l >> 4) * 8;
        w3p[i] = q8pack_w(w3, co * 576 + ci0, aw3[0]);
    } else if (id < 25344) {                // w2d: (ct*5 + kc)*64 + l
        int i = id - 13824;
        int l = i & 63, t = i >> 6;
        int kc = t % 5, ct = t / 5;
        int quad = l >> 4, m = l & 15;
        int tap = kc * 2 + (quad >> 1);
        unsigned long long v = 0;
        if (tap <= 8) {
            int mh = m - (quad & 1) * 8;    // lane's channel within this quad's octet?
            if (mh >= 0 && mh < 8) {
                // byte j whose k-channel c' = (quad&1)*8 + 2*(j&3) + (j>>2) equals m
                int j = (mh >> 1) | ((mh & 1) << 2);
                int q = (int)lsq_q(w2[(ct * 16 + m) * 9 + tap], aw2[0]);
                v = (unsigned long long)(unsigned)(q & 255) << (8 * j);
            }
        }
        w2d[i] = (long)v;
    } else if (id < 25920) {                // conv1 fused constants
        int c = id - 25344;
        float s = g1[c] / sqrtf(v1[c] + EPSF);
        float A = aw1[0] * ax1[0];
        float inv = 1.0f / ax2[0];          // exact (alpha = pow2)
        s1b1[c] = A * s * inv;
        s1b1[576 + c] = (b1[c] - m1[c] * s) * inv;
    } else if (id < 26496) {                // dw fused constants
        int c = id - 25920;
        float s = g2[c] / sqrtf(v2[c] + EPSF);
        float A = ax2[0] * aw2[0];
        float inv = 1.0f / ax3[0];
        s2b2[c] = A * s * inv;
        s2b2[576 + c] = (b2[c] - m2[c] * s) * inv;
    } else if (id < 26592) {                // conv3 fused constants
        int c = id - 26496;
        float s = g3[c] / sqrtf(v3[c] + EPSF);
        float A = ax3[0] * aw3[0];
        s3b3[c] = A * s;
        s3b3[96 + c] = b3[c] - m3[c] * s;
    }
}

// ---------------- K1: conv1 (i8 MFMA, A=weights B=acts) -> nibble-packed qh1n ----------
// grid (392 n-strips of 64, 3 co-strips of 192), 256 thr, no LDS, no barrier.
// Lane writes its 4 co as one ushort at byte ct*8+quad*2: channel order within the
// row is exactly ch = 2*byte + nibble (sequential) -- matches Phase B's lo/hi unpack.
__global__ __launch_bounds__(256, 4)
void conv1_k(const float* __restrict__ x, const long* __restrict__ w1p,
             const float* __restrict__ ax1, const float* __restrict__ s1b1,
             unsigned short* __restrict__ qh1n) {
    const int tid = threadIdx.x;
    const int w = tid >> 6, l = tid & 63;
    const int quad = l >> 4, c16 = l & 15;
    const int n0 = blockIdx.x * 64, cs = blockIdx.y;
    const int n = n0 + w * 16 + c16;                 // < 25088 always
    const int bi = n / 784, p = n - bi * 784;
    const float inv1 = 1.0f / ax1[0];                // exact for pow2 alpha

    long bfr[3];
    #pragma unroll
    for (int kc = 0; kc < 3; ++kc) {                 // quantize 8 input ch per quad
        const float* xs = x + (bi * 96 + kc * 32 + quad * 8) * 784 + p;
        unsigned long long v = 0;
        #pragma unroll
        for (int j = 0; j < 8; ++j) {
            float t = xs[j * 784] * inv1;
            t = fminf(fmaxf(t, -8.0f), 7.0f);
            int q = (int)rintf(t);
            v |= (unsigned long long)(q & 255) << (8 * j);
        }
        bfr[kc] = (long)v;
    }

    int4v acc[12];
    #pragma unroll
    for (int i = 0; i < 12; ++i) { acc[i][0] = 0; acc[i][1] = 0; acc[i][2] = 0; acc[i][3] = 0; }
    #pragma unroll
    for (int kc = 0; kc < 3; ++kc)
        #pragma unroll
        for (int ct = 0; ct < 12; ++ct)
            acc[ct] = __builtin_amdgcn_mfma_i32_16x16x32_i8(
                w1p[((cs * 12 + ct) * 3 + kc) * 64 + l], bfr[kc], acc[ct], 0, 0, 0);

    #pragma unroll
    for (int ct = 0; ct < 12; ++ct) {
        const int co0 = cs * 192 + ct * 16 + quad * 4;
        float4v S = *(const float4v*)(s1b1 + co0);
        float4v B = *(const float4v*)(s1b1 + 576 + co0);
        int pk = 0;
        #pragma unroll
        for (int r = 0; r < 4; ++r) {
            float t = fmaf((float)acc[ct][r], S[r], B[r]);
            t = fminf(fmaxf(t, 0.0f), 7.0f);         // ReLU6 + quant-clip fused
            pk |= ((int)rintf(t)) << (4 * r);        // nibble pack (values 0..7)
        }
        qh1n[n * 144 + cs * 48 + ct * 4 + quad] = (unsigned short)pk;
    }
}

// ---------------- K2: dw(MFMA) + conv3 fused, block = (batch, 1 output row) ----------
__global__ __launch_bounds__(512, 4)
void dwc3_k(const unsigned char* __restrict__ qh1n, const long* __restrict__ w2d,
            const long* __restrict__ w3p, const float* __restrict__ x,
            const float* __restrict__ s2b2, const float* __restrict__ s3b3,
            float* __restrict__ out) {
    __shared__ __align__(16) unsigned char h1[90 * H1S];   // 26.7 KB nibble slab
    __shared__ __align__(16) signed char  h2[32 * H2S];    // 18.8 KB int8
    const int tid = threadIdx.x;
    const int w = tid >> 6, l = tid & 63;
    const int quad = l >> 4, c16 = l & 15;
    const int qh = quad >> 1, ql = quad & 1;
    const int b = blockIdx.x;          // batch 0..31
    const int r = blockIdx.y;          // output row 0..27

    // ---- stage 3-row halo slab of qh1n into LDS (zero halo as data) ----
    #pragma unroll
    for (int i = 0; i < 4; ++i) {
        const int idx = tid + 512 * i;
        if (idx < 1620) {                            // 90 rows x 18 16B chunks
            const int rs = idx / 18, ch = idx - rs * 18;
            const int tr = rs / 30, colh = rs - tr * 30;
            const int col = colh - 1, ir = r - 1 + tr;
            int4v v = {0, 0, 0, 0};
            if ((unsigned)ir < 28u && (unsigned)col < 28u)
                v = *(const int4v*)(qh1n + (b * 784 + ir * 28 + col) * 288 + ch * 16);
            *(int4v*)(h1 + rs * H1S + ch * 16) = v;
        }
    }
    __syncthreads();

    // ---- Phase B: 3x3 depthwise as block-diagonal i8 MFMA (K=144, 5 chunks) ----
    int boff[5];                                     // per-lane tap offsets (hoisted)
    #pragma unroll
    for (int kc = 0; kc < 5; ++kc) {
        int tap = kc * 2 + qh;
        tap = min(tap, 8);                           // tap 9 has zero weight in w2d
        const int dh = tap / 3 - 1, dc = tap - (tap / 3) * 3 - 1;
        boff[kc] = (dh * 30 + dc) * H1S;
    }
    for (int t = w; t < 72; t += 8) {                // 2 pos-tiles x 36 ch-tiles
        const int pt = (t >= 36) ? 1 : 0, ct = t - pt * 36;
        const int pos = pt * 16 + c16;               // 0..31 (28..31 garbage, skipped later)
        const int col = min(pos, 27);
        const unsigned char* sbase = h1 + (31 + col) * H1S + ct * 8 + ql * 4;
        int4v acc; acc[0] = 0; acc[1] = 0; acc[2] = 0; acc[3] = 0;
        #pragma unroll
        for (int kc = 0; kc < 5; ++kc) {
            const unsigned v = *(const unsigned*)(sbase + boff[kc]);
            const unsigned lo = v & 0x0F0F0F0Fu;
            const unsigned hi = (v >> 4) & 0x0F0F0F0Fu;
            const long bf = (long)(((unsigned long long)hi << 32) | lo);
            acc = __builtin_amdgcn_mfma_i32_16x16x32_i8(
                w2d[(ct * 5 + kc) * 64 + l], bf, acc, 0, 0, 0);
        }
        const int c0 = ct * 16 + quad * 4;
        float4v S = *(const float4v*)(s2b2 + c0);
        float4v B = *(const float4v*)(s2b2 + 576 + c0);
        int pk = 0;
        #pragma unroll
        for (int rr = 0; rr < 4; ++rr) {
            float tt = fmaf((float)acc[rr], S[rr], B[rr]);
            tt = fminf(fmaxf(tt, 0.0f), 7.0f);
            pk |= ((int)rintf(tt)) << (8 * rr);
        }
        *(int*)(h2 + pos * H2S + c0) = pk;
    }
    __syncthreads();

    // ---- Phase C: conv3 (i8 MFMA, A=h2 B=weights) + BN + residual ----
    for (int t = w; t < 12; t += 8) {                // 2 pos-tiles x 6 co-tiles
        const int nt = t / 6, ct = t - nt * 6;
        int4v acc; acc[0] = 0; acc[1] = 0; acc[2] = 0; acc[3] = 0;
        const signed char* arow = h2 + (nt * 16 + c16) * H2S + quad * 8;
        #pragma unroll 6
        for (int kc = 0; kc < 18; ++kc)
            acc = __builtin_amdgcn_mfma_i32_16x16x32_i8(
                *(const long*)(arow + kc * 32),
                w3p[(ct * 18 + kc) * 64 + l], acc, 0, 0, 0);
        const int nloc = nt * 16 + quad * 4;          // 4 consecutive positions
        if (nloc < 28) {
            const int co = ct * 16 + c16;
            const float S = s3b3[co], Bv = s3b3[96 + co];
            const int off = (b * 96 + co) * 784 + r * 28 + nloc;  // 16B-aligned
            const float4v xr = *(const float4v*)(x + off);
            float4v o;
            #pragma unroll
            for (int rr = 0; rr < 4; ++rr)
                o[rr] = fmaf((float)acc[rr], S, Bv) + xr[rr];
            *(float4v*)(out + off) = o;
        }
    }
}

extern "C" void kernel_launch(void* const* d_in, const int* in_sizes, int n_in,
                              void* d_out, int out_size, void* d_ws, size_t ws_size,
                              hipStream_t stream) {
    const float* x   = (const float*)d_in[0];
    const float* w1  = (const float*)d_in[1];
    const float* w2  = (const float*)d_in[2];
    const float* w3  = (const float*)d_in[3];
    const float* aw1 = (const float*)d_in[4];
    const float* ax1 = (const float*)d_in[5];
    const float* g1  = (const float*)d_in[6];
    const float* b1  = (const float*)d_in[7];
    const float* m1  = (const float*)d_in[8];
    const float* v1  = (const float*)d_in[9];
    const float* aw2 = (const float*)d_in[10];
    const float* ax2 = (const float*)d_in[11];
    const float* g2  = (const float*)d_in[12];
    const float* b2  = (const float*)d_in[13];
    const float* m2  = (const float*)d_in[14];
    const float* v2  = (const float*)d_in[15];
    const float* aw3 = (const float*)d_in[16];
    const float* ax3 = (const float*)d_in[17];
    const float* g3  = (const float*)d_in[18];
    const float* b3  = (const float*)d_in[19];
    const float* m3  = (const float*)d_in[20];
    const float* v3  = (const float*)d_in[21];

    char* ws = (char*)d_ws;
    unsigned char* qh1n = (unsigned char*)(ws + QH1N_OFF);
    long* w1p = (long*)(ws + W1P_OFF);
    long* w3p = (long*)(ws + W3P_OFF);
    long* w2d = (long*)(ws + W2D_OFF);
    float* s1b1 = (float*)(ws + S1B1_OFF);
    float* s2b2 = (float*)(ws + S2B2_OFF);
    float* s3b3 = (float*)(ws + S3B3_OFF);

    float* out = (float*)d_out;

    prep_w<<<104, 256, 0, stream>>>(w1, w2, w3, aw1, ax1, ax2, aw2, ax3, aw3,
                                    g1, b1, m1, v1, g2, b2, m2, v2, g3, b3, m3, v3,
                                    w1p, w3p, w2d, s1b1, s2b2, s3b3);
    dim3 g1d(392, 3);
    conv1_k<<<g1d, 256, 0, stream>>>(x, w1p, ax1, s1b1, (unsigned short*)qh1n);
    dim3 g2d(32, 28);
    dwc3_k<<<g2d, 512, 0, stream>>>(qh1n, w2d, w3p, x, s2b2, s3b3, out);
}